// Round 4
// baseline (259.283 us; speedup 1.0000x reference)
//
#include <hip/hip_runtime.h>

// ---- problem constants ----
constexpr int N    = 20000;
constexpr int T    = 12;
constexpr int C    = 256;
constexpr int HIDN = 128;
constexpr int OUTD = 12;
constexpr int ER   = 30000;
constexpr int NFT  = 48;               // F*T floats per node
constexpr int EDGE_TOT = 5 * ER;       // 150000
constexpr int RN_TOT   = 5 * N;        // 100000 (region,node) bins
constexpr int SCAN_BLOCKS = 98;        // ceil(100001/1024)

// workspace layout (4-byte units)
constexpr int WS_DEG   = 0;        // [5N] float  (zeroed)
constexpr int WS_CNT   = 100000;   // [5N] int    (zeroed)
constexpr int WS_SCAN  = 200000;   // [100352] int  block-local exclusive scan
constexpr int WS_BSUM  = 300400;   // [98] int    per-block totals
constexpr int WS_AUX   = 300528;   // [128] int   scanned block offsets
constexpr int WS_ECOL  = 300656;   // [150000] int   CSR src
constexpr int WS_ECOEF = 450656;   // [150000] float CSR coef
constexpr int WS_XV    = 600656;   // [N*48] float  aggregated node features
constexpr int WS_MV    = 1560656;  // [10*C + T] float
constexpr int WS_WP    = 1563232;  // 32768 bf16 (16384 f): W1 B-fragments
constexpr int WS_W2T   = 1579616;  // [OUTD*HIDN] float

typedef __attribute__((ext_vector_type(8))) short short8;
typedef __attribute__((ext_vector_type(4))) float floatx4;

__device__ __forceinline__ short f2bf(float f) {   // RNE float->bf16
  unsigned u = __float_as_uint(f);
  u = u + 0x7fffu + ((u >> 16) & 1u);
  return (short)(u >> 16);
}

__device__ __forceinline__ void pick_region(
    int r,
    const int* e0, const int* e1, const int* e2, const int* e3, const int* e4,
    const float* a0, const float* a1, const float* a2, const float* a3, const float* a4,
    const int*& ei, const float*& ea) {
  switch (r) {
    case 0: ei = e0; ea = a0; break;
    case 1: ei = e1; ea = a1; break;
    case 2: ei = e2; ea = a2; break;
    case 3: ei = e3; ea = a3; break;
    default: ei = e4; ea = a4; break;
  }
}

// 1) weights prep: blocks 0-1 = collapsed gate weights (g=0: z, scale 1;
//    g=1: h, scale 2) + softmax(att); blocks 2.. = W1 MFMA-B pack + W2 transpose
__global__ void k_weights(const float* __restrict__ Wc_z, const float* __restrict__ bc_z,
                          const float* __restrict__ Wl_z, const float* __restrict__ bl_z,
                          const float* __restrict__ Wc_h, const float* __restrict__ bc_h,
                          const float* __restrict__ Wl_h, const float* __restrict__ bl_h,
                          const float* __restrict__ att, const float* __restrict__ W1,
                          const float* __restrict__ W2,
                          float* __restrict__ Mv, short* __restrict__ Wp,
                          float* __restrict__ W2t) {
  int b = blockIdx.x, tid = threadIdx.x;
  if (b < 2) {
    int g = b, k = tid;
    const float* Wc = g ? Wc_h : Wc_z;
    const float* bc = g ? bc_h : bc_z;
    const float* Wl = g ? Wl_h : Wl_z;
    const float* bl = g ? bl_h : bl_z;
    float scale = g ? 2.0f : 1.0f;
    float m0 = 0.f, m1 = 0.f, m2 = 0.f, m3 = 0.f, v = bl[k];
    for (int c = 0; c < C; c++) {
      float wl = Wl[c * C + k];
      m0 = fmaf(Wc[0 * C + c], wl, m0);
      m1 = fmaf(Wc[1 * C + c], wl, m1);
      m2 = fmaf(Wc[2 * C + c], wl, m2);
      m3 = fmaf(Wc[3 * C + c], wl, m3);
      v  = fmaf(bc[c], wl, v);
    }
    float* o = Mv + g * (5 * C);
    o[0 * C + k] = scale * m0;
    o[1 * C + k] = scale * m1;
    o[2 * C + k] = scale * m2;
    o[3 * C + k] = scale * m3;
    o[4 * C + k] = scale * v;
    if (g == 0 && k < T) {
      float amax = -3.0e38f;
      for (int t = 0; t < T; t++) amax = fmaxf(amax, att[t]);
      float s = 0.f;
      for (int t = 0; t < T; t++) s += __expf(att[t] - amax);
      Mv[10 * C + k] = __expf(att[k] - amax) / s;
    }
    return;
  }
  int idx = (b - 2) * 256 + tid;
  if (idx < 32768) {
    int j    = idx & 7;
    int lane = (idx >> 3) & 63;
    int ch   = (idx >> 9) & 7;
    int kt   = idx >> 12;
    int cin  = ch * 32 + (lane >> 4) * 8 + j;   // K index
    int kout = kt * 16 + (lane & 15);           // N index
    Wp[idx] = f2bf(W1[cin * HIDN + kout]);
  } else if (idx < 32768 + OUTD * HIDN) {
    int r = idx - 32768;
    int o = r >> 7, k = r & 127;
    W2t[r] = W2[k * OUTD + o];
  }
}

// 2) degree sums + bin counts (both zeroed by memset)
__global__ void k_deghist(const int* __restrict__ e0, const int* __restrict__ e1,
                          const int* __restrict__ e2, const int* __restrict__ e3,
                          const int* __restrict__ e4,
                          const float* __restrict__ a0, const float* __restrict__ a1,
                          const float* __restrict__ a2, const float* __restrict__ a3,
                          const float* __restrict__ a4,
                          float* __restrict__ deg, int* __restrict__ cnt) {
  int i = blockIdx.x * blockDim.x + threadIdx.x;
  if (i >= EDGE_TOT) return;
  int r = i / ER;
  int e = i - r * ER;
  const int* ei; const float* ea;
  pick_region(r, e0, e1, e2, e3, e4, a0, a1, a2, a3, a4, ei, ea);
  int rn = r * N + ei[ER + e];
  atomicAdd(&deg[rn], ea[e]);
  atomicAdd(&cnt[rn], 1);
}

// 3a) block-local exclusive scan of cnt (1024 elems/block) + block totals
__global__ __launch_bounds__(256) void k_scan1(const int* __restrict__ cnt,
                                               int* __restrict__ scanv,
                                               int* __restrict__ bsum) {
  __shared__ int sd[256];
  int tid = threadIdx.x;
  int base = blockIdx.x * 1024 + tid * 4;
  int v[4], s = 0;
#pragma unroll
  for (int j = 0; j < 4; j++) {
    v[j] = s;
    int idx = base + j;
    s += (idx < RN_TOT) ? cnt[idx] : 0;
  }
  sd[tid] = s;
  __syncthreads();
  for (int off = 1; off < 256; off <<= 1) {
    int t = (tid >= off) ? sd[tid - off] : 0;
    __syncthreads();
    sd[tid] += t;
    __syncthreads();
  }
  int texcl = sd[tid] - s;
#pragma unroll
  for (int j = 0; j < 4; j++) scanv[base + j] = texcl + v[j];
  if (tid == 255) bsum[blockIdx.x] = sd[255];
}

// 3b) exclusive scan of the 98 block totals
__global__ __launch_bounds__(128) void k_scan2(const int* __restrict__ bsum,
                                               int* __restrict__ aux) {
  __shared__ int sd[128];
  int tid = threadIdx.x;
  int val = (tid < SCAN_BLOCKS) ? bsum[tid] : 0;
  sd[tid] = val;
  __syncthreads();
  for (int off = 1; off < 128; off <<= 1) {
    int t = (tid >= off) ? sd[tid - off] : 0;
    __syncthreads();
    sd[tid] += t;
    __syncthreads();
  }
  aux[tid] = sd[tid] - val;
}

// 4) fill CSR: coef fused; slot via atomic post-decrement of cnt
__global__ void k_fill(const int* __restrict__ e0, const int* __restrict__ e1,
                       const int* __restrict__ e2, const int* __restrict__ e3,
                       const int* __restrict__ e4,
                       const float* __restrict__ a0, const float* __restrict__ a1,
                       const float* __restrict__ a2, const float* __restrict__ a3,
                       const float* __restrict__ a4,
                       const float* __restrict__ deg, int* __restrict__ cnt,
                       const int* __restrict__ scanv, const int* __restrict__ aux,
                       int* __restrict__ ecol, float* __restrict__ ecoef) {
  int i = blockIdx.x * blockDim.x + threadIdx.x;
  if (i >= EDGE_TOT) return;
  int r = i / ER;
  int e = i - r * ER;
  const int* ei; const float* ea;
  pick_region(r, e0, e1, e2, e3, e4, a0, a1, a2, a3, a4, ei, ea);
  int src = ei[e];
  int dst = ei[ER + e];
  int rn = r * N + dst;
  float cf = rsqrtf(deg[r * N + src] + 1.0f) * ea[e] * rsqrtf(deg[rn] + 1.0f);
  int old = atomicSub(&cnt[rn], 1);
  int slot = scanv[rn] + aux[rn >> 10] + old - 1;
  ecol[slot] = src;
  ecoef[slot] = cf;
}

// 5) gather: one wave per node. xv[n][q] = s*x[n][q] + sum_edges cf*x[src][q]
__global__ __launch_bounds__(256) void k_gather(
    const float* __restrict__ x, const float* __restrict__ deg,
    const int* __restrict__ scanv, const int* __restrict__ aux,
    const int* __restrict__ ecol, const float* __restrict__ ecoef,
    float* __restrict__ xv) {
  int wave = threadIdx.x >> 6, lane = threadIdx.x & 63;
  int n = blockIdx.x * 4 + wave;
  int q = lane < NFT ? lane : NFT - 1;   // clamp idle lanes (no OOB)
  float s = 0.f;
#pragma unroll
  for (int r = 0; r < 5; r++) s += 1.0f / (deg[r * N + n] + 1.0f);
  float acc = s * x[n * NFT + q];
#pragma unroll
  for (int r = 0; r < 5; r++) {
    int rn = r * N + n;
    int b0 = scanv[rn] + aux[rn >> 10];
    int b1 = scanv[rn + 1] + aux[(rn + 1) >> 10];
    for (int j = b0; j < b1; j++) {
      int src = ecol[j];
      float cf = ecoef[j];
      acc = fmaf(cf, x[src * NFT + q], acc);
    }
  }
  if (lane < NFT) xv[n * NFT + q] = acc;
}

// 6) gates + temporal attention pooling. One wave per node, lane owns 4 channels.
//    az oriented so (1-Z) = 1/(1+e^az); one rcp serves both denominators.
__global__ __launch_bounds__(256) void k_gates(
    const float* __restrict__ xv, const float* __restrict__ Mv,
    float* __restrict__ h_out) {
  int wave = threadIdx.x >> 6, lane = threadIdx.x & 63;
  int n = blockIdx.x * 4 + wave;
  int c0 = lane << 2;
  const float* Mz = Mv;
  const float* Mh = Mv + 5 * C;
  float mz[4][4], mh[4][4], vz[4], vh[4];
#pragma unroll
  for (int f = 0; f < 4; f++) {
    float4 t1 = *(const float4*)(Mz + f * C + c0);
    mz[f][0] = t1.x; mz[f][1] = t1.y; mz[f][2] = t1.z; mz[f][3] = t1.w;
    float4 t2 = *(const float4*)(Mh + f * C + c0);
    mh[f][0] = t2.x; mh[f][1] = t2.y; mh[f][2] = t2.z; mh[f][3] = t2.w;
  }
  {
    float4 t1 = *(const float4*)(Mz + 4 * C + c0);
    vz[0] = t1.x; vz[1] = t1.y; vz[2] = t1.z; vz[3] = t1.w;
    float4 t2 = *(const float4*)(Mh + 4 * C + c0);
    vh[0] = t2.x; vh[1] = t2.y; vh[2] = t2.z; vh[3] = t2.w;
  }
  float p[T];
#pragma unroll
  for (int t = 0; t < T; t++) p[t] = Mv[10 * C + t];

  const float* xr = xv + n * NFT;
  float acc[4] = {0.f, 0.f, 0.f, 0.f};
#pragma unroll
  for (int tb = 0; tb < 3; tb++) {
    float4 xf0 = *(const float4*)(xr + 0 * T + tb * 4);
    float4 xf1 = *(const float4*)(xr + 1 * T + tb * 4);
    float4 xf2 = *(const float4*)(xr + 2 * T + tb * 4);
    float4 xf3 = *(const float4*)(xr + 3 * T + tb * 4);
    float xs0[4] = {xf0.x, xf0.y, xf0.z, xf0.w};
    float xs1[4] = {xf1.x, xf1.y, xf1.z, xf1.w};
    float xs2[4] = {xf2.x, xf2.y, xf2.z, xf2.w};
    float xs3[4] = {xf3.x, xf3.y, xf3.z, xf3.w};
#pragma unroll
    for (int tt = 0; tt < 4; tt++) {
      int t = tb * 4 + tt;
      float x0 = xs0[tt], x1 = xs1[tt], x2 = xs2[tt], x3 = xs3[tt];
#pragma unroll
      for (int j = 0; j < 4; j++) {
        float az = fmaf(mz[0][j], x0, fmaf(mz[1][j], x1, fmaf(mz[2][j], x2, fmaf(mz[3][j], x3, vz[j]))));
        float ah = fmaf(mh[0][j], x0, fmaf(mh[1][j], x1, fmaf(mh[2][j], x2, fmaf(mh[3][j], x3, vh[j]))));
        float e1 = __expf(az);                        // e^{az}
        float e2 = __expf(ah);                        // e^{2*ah_true}
        float a1 = 1.0f + e1, a2 = 1.0f + e2;
        float rD = __builtin_amdgcn_rcpf(a1 * a2);
        float w  = rD * a2;                           // 1-Z
        float u  = rD * a1;                           // 1/(1+e2)
        float th = fmaf(-2.0f, u, 1.0f);              // tanh
        acc[j] = fmaf(p[t], w * th, acc[j]);
      }
    }
  }
  float4 o = {acc[0], acc[1], acc[2], acc[3]};
  *(float4*)(h_out + n * C + c0) = o;
}

// 7) MLP via bf16 MFMA (unchanged from R3)
__global__ __launch_bounds__(256) void k_mlp(
    const float* __restrict__ h_in, const short* __restrict__ Wp,
    const float* __restrict__ b1, const float* __restrict__ W2t,
    const float* __restrict__ b2, float* __restrict__ y_out) {
  __shared__ float y1s[4][16][132];
  int tid = threadIdx.x;
  int wave = tid >> 6, lane = tid & 63;
  int quad = lane >> 4, col = lane & 15;
  int nA = blockIdx.x * 64 + wave * 16 + col;
  if (nA > N - 1) nA = N - 1;
  const float* hrow = h_in + nA * C;

  floatx4 acc[8];
#pragma unroll
  for (int kt = 0; kt < 8; kt++) acc[kt] = {0.f, 0.f, 0.f, 0.f};
#pragma unroll
  for (int ch = 0; ch < 8; ch++) {
    float4 ha = *(const float4*)(hrow + ch * 32 + quad * 8);
    float4 hb = *(const float4*)(hrow + ch * 32 + quad * 8 + 4);
    short8 a;
    a[0] = f2bf(fmaxf(ha.x, 0.f)); a[1] = f2bf(fmaxf(ha.y, 0.f));
    a[2] = f2bf(fmaxf(ha.z, 0.f)); a[3] = f2bf(fmaxf(ha.w, 0.f));
    a[4] = f2bf(fmaxf(hb.x, 0.f)); a[5] = f2bf(fmaxf(hb.y, 0.f));
    a[6] = f2bf(fmaxf(hb.z, 0.f)); a[7] = f2bf(fmaxf(hb.w, 0.f));
#pragma unroll
    for (int kt = 0; kt < 8; kt++) {
      short8 b = ((const short8*)Wp)[(kt * 8 + ch) * 64 + lane];
      acc[kt] = __builtin_amdgcn_mfma_f32_16x16x32_bf16(a, b, acc[kt], 0, 0, 0);
    }
  }
#pragma unroll
  for (int kt = 0; kt < 8; kt++) {
    float bias = b1[kt * 16 + col];
#pragma unroll
    for (int r = 0; r < 4; r++)
      y1s[wave][quad * 4 + r][kt * 16 + col] = fmaxf(acc[kt][r] + bias, 0.f);
  }
  __syncthreads();
#pragma unroll
  for (int rep = 0; rep < 3; rep++) {
    int idx = rep * 256 + tid;
    int nl = idx / 12, o = idx - nl * 12;
    int node = blockIdx.x * 64 + nl;
    float sacc = b2[o];
    const float* yr = &y1s[nl >> 4][nl & 15][0];
    const float* wr = W2t + o * HIDN;
#pragma unroll 8
    for (int k4 = 0; k4 < 32; k4++) {
      float4 yv = *(const float4*)(yr + 4 * k4);
      float4 wv = *(const float4*)(wr + 4 * k4);
      sacc = fmaf(yv.x, wv.x, fmaf(yv.y, wv.y, fmaf(yv.z, wv.z, fmaf(yv.w, wv.w, sacc))));
    }
    if (node < N) y_out[node * OUTD + o] = sacc;
  }
}

extern "C" void kernel_launch(void* const* d_in, const int* in_sizes, int n_in,
                              void* d_out, int out_size, void* d_ws, size_t ws_size,
                              hipStream_t stream) {
  const float* x   = (const float*)d_in[0];
  // d_in[1] full-graph edge_index: provably unused
  const int* eIA = (const int*)d_in[2];
  const int* eKS = (const int*)d_in[3];
  const int* eKY = (const int*)d_in[4];
  const int* eOH = (const int*)d_in[5];
  const int* eWI = (const int*)d_in[6];
  const float* aIA = (const float*)d_in[7];
  const float* aKS = (const float*)d_in[8];
  const float* aKY = (const float*)d_in[9];
  const float* aOH = (const float*)d_in[10];
  const float* aWI = (const float*)d_in[11];
  const float* Wc_z = (const float*)d_in[12];
  const float* bc_z = (const float*)d_in[13];
  const float* Wl_z = (const float*)d_in[14];
  const float* bl_z = (const float*)d_in[15];
  // r-gate params (16..19) cannot influence the output (H=0)
  const float* Wc_h = (const float*)d_in[20];
  const float* bc_h = (const float*)d_in[21];
  const float* Wl_h = (const float*)d_in[22];
  const float* bl_h = (const float*)d_in[23];
  const float* att  = (const float*)d_in[24];
  const float* W1   = (const float*)d_in[25];
  const float* b1   = (const float*)d_in[26];
  const float* W2   = (const float*)d_in[27];
  const float* b2   = (const float*)d_in[28];

  float* ws    = (float*)d_ws;
  float* deg   = ws + WS_DEG;
  int*   cnt   = (int*)(ws + WS_CNT);
  int*   scanv = (int*)(ws + WS_SCAN);
  int*   bsum  = (int*)(ws + WS_BSUM);
  int*   aux   = (int*)(ws + WS_AUX);
  int*   ecol  = (int*)(ws + WS_ECOL);
  float* ecoef = ws + WS_ECOEF;
  float* xvb   = ws + WS_XV;
  float* Mv    = ws + WS_MV;
  short* Wp    = (short*)(ws + WS_WP);
  float* W2t   = ws + WS_W2T;

  float* y_out = (float*)d_out;            // [N,12]
  float* h_out = y_out + N * OUTD;         // [N,256]

  hipMemsetAsync(deg, 0, 2 * RN_TOT * sizeof(float), stream);  // deg + cnt

  k_weights<<<136, 256, 0, stream>>>(Wc_z, bc_z, Wl_z, bl_z, Wc_h, bc_h, Wl_h, bl_h,
                                     att, W1, W2, Mv, Wp, W2t);
  k_deghist<<<(EDGE_TOT + 255) / 256, 256, 0, stream>>>(eIA, eKS, eKY, eOH, eWI,
                                                        aIA, aKS, aKY, aOH, aWI,
                                                        deg, cnt);
  k_scan1<<<SCAN_BLOCKS, 256, 0, stream>>>(cnt, scanv, bsum);
  k_scan2<<<1, 128, 0, stream>>>(bsum, aux);
  k_fill<<<(EDGE_TOT + 255) / 256, 256, 0, stream>>>(eIA, eKS, eKY, eOH, eWI,
                                                     aIA, aKS, aKY, aOH, aWI,
                                                     deg, cnt, scanv, aux, ecol, ecoef);
  k_gather<<<N / 4, 256, 0, stream>>>(x, deg, scanv, aux, ecol, ecoef, xvb);
  k_gates<<<N / 4, 256, 0, stream>>>(xvb, Mv, h_out);
  k_mlp<<<(N + 63) / 64, 256, 0, stream>>>(h_out, Wp, b1, W2t, b2, y_out);
}

// Round 5
// 219.302 us; speedup vs baseline: 1.1823x; 1.1823x over previous
//
#include <hip/hip_runtime.h>

// ---- problem constants ----
constexpr int N    = 20000;
constexpr int T    = 12;
constexpr int C    = 256;
constexpr int HIDN = 128;
constexpr int OUTD = 12;
constexpr int ER   = 30000;
constexpr int NFT  = 48;               // F*T floats per node
constexpr int EDGE_TOT = 5 * ER;       // 150000
constexpr int RN_TOT   = 5 * N;        // 100000 (region,node) bins
constexpr int CAP      = 24;           // bucket capacity (mean deg 1.5; P(>24)~1e-19)

// workspace layout (4-byte units)
constexpr int WS_DEG    = 0;          // [100000] float (zeroed in k_prep)
constexpr int WS_CNT    = 100000;     // [100000] int   (zeroed in k_prep)
constexpr int WS_BUCKET = 200000;     // [100000*CAP*2] int2 (src, w-bits)
constexpr int WS_XV     = 5000000;    // [N*48] float aggregated features
constexpr int WS_MV     = 5960000;    // [10*C + T] float
constexpr int WS_WP     = 5963000;    // 32768 bf16 = 16384 floats (W1 B-frags)
constexpr int WS_W2T    = 5980000;    // [OUTD*HIDN] float

constexpr int ZERO_N    = 2 * RN_TOT;           // ints to zero (deg+cnt)
constexpr int PREP_IDX  = 32768 + 1536 + ZERO_N; // pack + zero work items

typedef __attribute__((ext_vector_type(8))) short short8;
typedef __attribute__((ext_vector_type(4))) float floatx4;

__device__ __forceinline__ short f2bf(float f) {   // RNE float->bf16
  unsigned u = __float_as_uint(f);
  u = u + 0x7fffu + ((u >> 16) & 1u);
  return (short)(u >> 16);
}

// 1) prep: blocks 0-1 collapse gate weights (g=0: z, scale 1; g=1: h, scale 2)
//    + softmax(att); blocks 2.. pack W1 into MFMA-B bf16 frags, transpose W2,
//    and zero deg+cnt.
__global__ void k_prep(const float* __restrict__ Wc_z, const float* __restrict__ bc_z,
                       const float* __restrict__ Wl_z, const float* __restrict__ bl_z,
                       const float* __restrict__ Wc_h, const float* __restrict__ bc_h,
                       const float* __restrict__ Wl_h, const float* __restrict__ bl_h,
                       const float* __restrict__ att, const float* __restrict__ W1,
                       const float* __restrict__ W2,
                       float* __restrict__ Mv, short* __restrict__ Wp,
                       float* __restrict__ W2t, int* __restrict__ zero_base) {
  int b = blockIdx.x, tid = threadIdx.x;
  if (b < 2) {
    int g = b, k = tid;
    const float* Wc = g ? Wc_h : Wc_z;
    const float* bc = g ? bc_h : bc_z;
    const float* Wl = g ? Wl_h : Wl_z;
    const float* bl = g ? bl_h : bl_z;
    float scale = g ? 2.0f : 1.0f;
    float m0 = 0.f, m1 = 0.f, m2 = 0.f, m3 = 0.f, v = bl[k];
    for (int c = 0; c < C; c++) {
      float wl = Wl[c * C + k];
      m0 = fmaf(Wc[0 * C + c], wl, m0);
      m1 = fmaf(Wc[1 * C + c], wl, m1);
      m2 = fmaf(Wc[2 * C + c], wl, m2);
      m3 = fmaf(Wc[3 * C + c], wl, m3);
      v  = fmaf(bc[c], wl, v);
    }
    float* o = Mv + g * (5 * C);
    o[0 * C + k] = scale * m0;
    o[1 * C + k] = scale * m1;
    o[2 * C + k] = scale * m2;
    o[3 * C + k] = scale * m3;
    o[4 * C + k] = scale * v;
    if (g == 0 && k < T) {
      float amax = -3.0e38f;
      for (int t = 0; t < T; t++) amax = fmaxf(amax, att[t]);
      float s = 0.f;
      for (int t = 0; t < T; t++) s += __expf(att[t] - amax);
      Mv[10 * C + k] = __expf(att[k] - amax) / s;
    }
    return;
  }
  int idx = (b - 2) * 256 + tid;
  if (idx < 32768) {
    int j    = idx & 7;
    int lane = (idx >> 3) & 63;
    int ch   = (idx >> 9) & 7;
    int kt   = idx >> 12;
    int cin  = ch * 32 + (lane >> 4) * 8 + j;   // K index
    int kout = kt * 16 + (lane & 15);           // N index
    Wp[idx] = f2bf(W1[cin * HIDN + kout]);
  } else if (idx < 32768 + 1536) {
    int r = idx - 32768;
    int o = r >> 7, k = r & 127;
    W2t[r] = W2[k * OUTD + o];
  } else if (idx < PREP_IDX) {
    zero_base[idx - (32768 + 1536)] = 0;        // deg + cnt
  }
}

// 2) single edge pass: degree atomics + bucket fill (coef deferred to gather)
__global__ void k_edges(const int* __restrict__ e0, const int* __restrict__ e1,
                        const int* __restrict__ e2, const int* __restrict__ e3,
                        const int* __restrict__ e4,
                        const float* __restrict__ a0, const float* __restrict__ a1,
                        const float* __restrict__ a2, const float* __restrict__ a3,
                        const float* __restrict__ a4,
                        float* __restrict__ deg, int* __restrict__ cnt,
                        int2* __restrict__ bucket) {
  int i = blockIdx.x * blockDim.x + threadIdx.x;
  if (i >= EDGE_TOT) return;
  int r = i / ER;
  int e = i - r * ER;
  const int* ei; const float* ea;
  switch (r) {
    case 0: ei = e0; ea = a0; break;
    case 1: ei = e1; ea = a1; break;
    case 2: ei = e2; ea = a2; break;
    case 3: ei = e3; ea = a3; break;
    default: ei = e4; ea = a4; break;
  }
  int src = ei[e];
  int dst = ei[ER + e];
  float w = ea[e];
  int rn = r * N + dst;
  atomicAdd(&deg[rn], w);
  int slot = atomicAdd(&cnt[rn], 1);
  if (slot < CAP) bucket[rn * CAP + slot] = make_int2(src, __float_as_int(w));
}

// 3) gather: one wave per node, lane = feature q (48 of 64 active).
//    xv[n][q] = s*x[n][q] + sum_r sum_e coef*x[src][q];  coef computed inline.
__global__ __launch_bounds__(256) void k_gather(
    const float* __restrict__ x, const float* __restrict__ deg,
    const int* __restrict__ cnt, const int2* __restrict__ bucket,
    float* __restrict__ xv) {
  int wave = threadIdx.x >> 6, lane = threadIdx.x & 63;
  int n = blockIdx.x * 4 + wave;
  int q = lane < NFT ? lane : NFT - 1;   // clamp idle lanes
  float s = 0.f;
#pragma unroll
  for (int r = 0; r < 5; r++) s += 1.0f / (deg[r * N + n] + 1.0f);
  float acc = s * x[n * NFT + q];
#pragma unroll
  for (int r = 0; r < 5; r++) {
    int rn = r * N + n;
    int cv = cnt[rn];
    if (cv > CAP) cv = CAP;
    float dv_dst = rsqrtf(deg[rn] + 1.0f);
    const int2* bk = bucket + rn * CAP;
    for (int j = 0; j < cv; j++) {
      int2 m = bk[j];
      int src = m.x;
      float w = __int_as_float(m.y);
      float cf = rsqrtf(deg[r * N + src] + 1.0f) * w * dv_dst;
      acc = fmaf(cf, x[src * NFT + q], acc);
    }
  }
  if (lane < NFT) xv[n * NFT + q] = acc;
}

// 4) fused gates + attention pooling + MLP.  Block = 16 nodes, 4 waves;
//    wave w computes h for nodes w*4..w*4+3 (lane owns 4 channels, M in regs),
//    writes fp32 h to global and bf16 h to LDS in MFMA-A order; then the 4
//    waves do the 16x128 layer-1 MFMA GEMM (kt split 2/wave) + layer 2.
__global__ __launch_bounds__(256) void k_gates_mlp(
    const float* __restrict__ xv, const float* __restrict__ Mv,
    const short* __restrict__ Wp, const float* __restrict__ b1,
    const float* __restrict__ W2t, const float* __restrict__ b2,
    float* __restrict__ y_out, float* __restrict__ h_out) {
  __shared__ short hs[16][264];       // bf16 relu(h), row pad 256->264 (bank-clean)
  __shared__ float y1s[16][132];      // fp32 layer-1 out, pad 128->132
  int tid = threadIdx.x;
  int wave = tid >> 6, lane = tid & 63;
  int quad = lane >> 4, col = lane & 15;
  int n0 = blockIdx.x * 16;

  // ---- gates phase (validated R4 math) ----
  int c0 = lane << 2;
  const float* Mz = Mv;
  const float* Mh = Mv + 5 * C;
  float mz[4][4], mh[4][4], vz[4], vh[4];
#pragma unroll
  for (int f = 0; f < 4; f++) {
    float4 t1 = *(const float4*)(Mz + f * C + c0);
    mz[f][0] = t1.x; mz[f][1] = t1.y; mz[f][2] = t1.z; mz[f][3] = t1.w;
    float4 t2 = *(const float4*)(Mh + f * C + c0);
    mh[f][0] = t2.x; mh[f][1] = t2.y; mh[f][2] = t2.z; mh[f][3] = t2.w;
  }
  {
    float4 t1 = *(const float4*)(Mz + 4 * C + c0);
    vz[0] = t1.x; vz[1] = t1.y; vz[2] = t1.z; vz[3] = t1.w;
    float4 t2 = *(const float4*)(Mh + 4 * C + c0);
    vh[0] = t2.x; vh[1] = t2.y; vh[2] = t2.z; vh[3] = t2.w;
  }
  float p[T];
#pragma unroll
  for (int t = 0; t < T; t++) p[t] = Mv[10 * C + t];

#pragma unroll
  for (int nl = 0; nl < 4; nl++) {
    int rl = wave * 4 + nl;             // local node 0..15
    int n = n0 + rl;
    const float* xr = xv + n * NFT;
    float acc[4] = {0.f, 0.f, 0.f, 0.f};
#pragma unroll
    for (int tb = 0; tb < 3; tb++) {
      float4 xf0 = *(const float4*)(xr + 0 * T + tb * 4);
      float4 xf1 = *(const float4*)(xr + 1 * T + tb * 4);
      float4 xf2 = *(const float4*)(xr + 2 * T + tb * 4);
      float4 xf3 = *(const float4*)(xr + 3 * T + tb * 4);
      float xs0[4] = {xf0.x, xf0.y, xf0.z, xf0.w};
      float xs1[4] = {xf1.x, xf1.y, xf1.z, xf1.w};
      float xs2[4] = {xf2.x, xf2.y, xf2.z, xf2.w};
      float xs3[4] = {xf3.x, xf3.y, xf3.z, xf3.w};
#pragma unroll
      for (int tt = 0; tt < 4; tt++) {
        int t = tb * 4 + tt;
        float x0 = xs0[tt], x1 = xs1[tt], x2 = xs2[tt], x3 = xs3[tt];
#pragma unroll
        for (int j = 0; j < 4; j++) {
          float az = fmaf(mz[0][j], x0, fmaf(mz[1][j], x1, fmaf(mz[2][j], x2, fmaf(mz[3][j], x3, vz[j]))));
          float ah = fmaf(mh[0][j], x0, fmaf(mh[1][j], x1, fmaf(mh[2][j], x2, fmaf(mh[3][j], x3, vh[j]))));
          float e1 = __expf(az);                        // e^{az}
          float e2 = __expf(ah);                        // e^{2*ah_true}
          float a1 = 1.0f + e1, a2 = 1.0f + e2;
          float rD = __builtin_amdgcn_rcpf(a1 * a2);
          float w  = rD * a2;                           // 1-Z
          float u  = rD * a1;                           // 1/(1+e2)
          float th = fmaf(-2.0f, u, 1.0f);              // tanh
          acc[j] = fmaf(p[t], w * th, acc[j]);
        }
      }
    }
    float4 o = {acc[0], acc[1], acc[2], acc[3]};
    *(float4*)(h_out + n * C + c0) = o;                 // required output (fp32)
    // relu + bf16 into LDS, MFMA-A row = local node
    unsigned lo = (unsigned short)f2bf(fmaxf(acc[0], 0.f)) |
                  ((unsigned)(unsigned short)f2bf(fmaxf(acc[1], 0.f)) << 16);
    unsigned hi = (unsigned short)f2bf(fmaxf(acc[2], 0.f)) |
                  ((unsigned)(unsigned short)f2bf(fmaxf(acc[3], 0.f)) << 16);
    *(int2*)&hs[rl][c0] = make_int2((int)lo, (int)hi);
  }
  __syncthreads();

  // ---- layer 1: 16x128 = 16 MFMAs per wave (kt = wave*2, wave*2+1) ----
  floatx4 acc2[2];
  acc2[0] = {0.f, 0.f, 0.f, 0.f};
  acc2[1] = {0.f, 0.f, 0.f, 0.f};
#pragma unroll
  for (int ch = 0; ch < 8; ch++) {
    short8 a = *(const short8*)&hs[col][ch * 32 + quad * 8];
#pragma unroll
    for (int kk = 0; kk < 2; kk++) {
      short8 b = ((const short8*)Wp)[((wave * 2 + kk) * 8 + ch) * 64 + lane];
      acc2[kk] = __builtin_amdgcn_mfma_f32_16x16x32_bf16(a, b, acc2[kk], 0, 0, 0);
    }
  }
#pragma unroll
  for (int kk = 0; kk < 2; kk++) {
    int kt = wave * 2 + kk;
    float bias = b1[kt * 16 + col];
#pragma unroll
    for (int r = 0; r < 4; r++)
      y1s[quad * 4 + r][kt * 16 + col] = fmaxf(acc2[kk][r] + bias, 0.f);
  }
  __syncthreads();

  // ---- layer 2: 16 nodes x 12 outputs = 192 threads ----
  if (tid < 16 * OUTD) {
    int nl = tid / OUTD, o = tid - nl * OUTD;
    float sacc = b2[o];
    const float* yr = &y1s[nl][0];
    const float* wr = W2t + o * HIDN;
#pragma unroll 8
    for (int k4 = 0; k4 < 32; k4++) {
      float4 yv = *(const float4*)(yr + 4 * k4);
      float4 wv = *(const float4*)(wr + 4 * k4);
      sacc = fmaf(yv.x, wv.x, fmaf(yv.y, wv.y, fmaf(yv.z, wv.z, fmaf(yv.w, wv.w, sacc))));
    }
    y_out[(n0 + nl) * OUTD + o] = sacc;
  }
}

extern "C" void kernel_launch(void* const* d_in, const int* in_sizes, int n_in,
                              void* d_out, int out_size, void* d_ws, size_t ws_size,
                              hipStream_t stream) {
  const float* x   = (const float*)d_in[0];
  // d_in[1] full-graph edge_index: provably unused
  const int* eIA = (const int*)d_in[2];
  const int* eKS = (const int*)d_in[3];
  const int* eKY = (const int*)d_in[4];
  const int* eOH = (const int*)d_in[5];
  const int* eWI = (const int*)d_in[6];
  const float* aIA = (const float*)d_in[7];
  const float* aKS = (const float*)d_in[8];
  const float* aKY = (const float*)d_in[9];
  const float* aOH = (const float*)d_in[10];
  const float* aWI = (const float*)d_in[11];
  const float* Wc_z = (const float*)d_in[12];
  const float* bc_z = (const float*)d_in[13];
  const float* Wl_z = (const float*)d_in[14];
  const float* bl_z = (const float*)d_in[15];
  // r-gate params (16..19) cannot influence the output (H=0)
  const float* Wc_h = (const float*)d_in[20];
  const float* bc_h = (const float*)d_in[21];
  const float* Wl_h = (const float*)d_in[22];
  const float* bl_h = (const float*)d_in[23];
  const float* att  = (const float*)d_in[24];
  const float* W1   = (const float*)d_in[25];
  const float* b1   = (const float*)d_in[26];
  const float* W2   = (const float*)d_in[27];
  const float* b2   = (const float*)d_in[28];

  float* ws     = (float*)d_ws;
  float* deg    = ws + WS_DEG;
  int*   cnt    = (int*)(ws + WS_CNT);
  int2*  bucket = (int2*)(ws + WS_BUCKET);
  float* xvb    = ws + WS_XV;
  float* Mv     = ws + WS_MV;
  short* Wp     = (short*)(ws + WS_WP);
  float* W2t    = ws + WS_W2T;

  float* y_out = (float*)d_out;            // [N,12]
  float* h_out = y_out + N * OUTD;         // [N,256]

  int prep_grid = 2 + (PREP_IDX + 255) / 256;
  k_prep<<<prep_grid, 256, 0, stream>>>(Wc_z, bc_z, Wl_z, bl_z, Wc_h, bc_h,
                                        Wl_h, bl_h, att, W1, W2,
                                        Mv, Wp, W2t, (int*)deg);
  k_edges<<<(EDGE_TOT + 255) / 256, 256, 0, stream>>>(eIA, eKS, eKY, eOH, eWI,
                                                      aIA, aKS, aKY, aOH, aWI,
                                                      deg, cnt, bucket);
  k_gather<<<N / 4, 256, 0, stream>>>(x, deg, cnt, bucket, xvb);
  k_gates_mlp<<<N / 16, 256, 0, stream>>>(xvb, Mv, Wp, b1, W2t, b2, y_out, h_out);
}